// Round 11
// baseline (222.371 us; speedup 1.0000x reference)
//
#include <hip/hip_runtime.h>

#define B_G   100
#define N_PER 1000
#define E_PER 12000
#define NTOT  (B_G * N_PER)
#define ETOT  (B_G * E_PER)
#define KSEL  800
#define EPT   12

// ---- workspace layout (bytes) ----
#define FLAG1B 0u          // u32[200]: z-exchange flags
#define FLAG2B 1024u       // u32[100]: h2/keys flags
#define ZXB    4096u       // z exchange [1000][64] fp8 per graph, stride 64000
#define SREDXB 6404096u    // f32[16][64] per graph, stride 4096
#define H2XB   6813696u    // h2 rows 512..999 (31232 B) per graph, stride 32768
#define KEYXB  10090496u   // u64[512] per graph, stride 4096
#define WSNEED 10500096u

#define SPINCAP 200000     // ~40ms cap: no hang possible, bounded diagnostic

typedef __attribute__((ext_vector_type(8))) short short8;
typedef __attribute__((ext_vector_type(4))) float float4_;

__device__ __forceinline__ unsigned short f2bf(float f) {
    unsigned u = __float_as_uint(f);
    u += 0x7fffu + ((u >> 16) & 1u);          // RNE
    return (unsigned short)(u >> 16);
}
__device__ __forceinline__ float upk(unsigned q) {          // bf16 ew in hi16
    return __uint_as_float(q & 0xFFFF0000u);
}
// fp8 e4m3 (z>=0): raw decode = true_value * 2^-120 (exact, incl subnormals)
__device__ __forceinline__ float dec_raw(unsigned byte7f) { // pass (b&0x7f)
    return __uint_as_float(byte7f << 20);
}
__device__ __forceinline__ unsigned enc_fp8(float z) {      // z >= 0, z < 448
    unsigned u = __float_as_uint(z * 0x1p-120f);
    u += 0x7FFFFu + ((u >> 20) & 1u);                       // RNE at bit 20
    return u >> 20;
}

// ---- CSR build: edge load, count, scan, fill. Ends with a barrier. ----
#define BUILD_BODY(PRE) do {                                                   \
    int esrc[EPT], edst[EPT]; float eww[EPT];                                  \
    int ne = (tid < (E_PER - (EPT - 1) * 1024)) ? EPT : EPT - 1;               \
    _Pragma("unroll")                                                          \
    for (int i = 0; i < EPT; i++) {                                            \
        if (i < ne) {                                                          \
            int e = tid + i * 1024;                                            \
            esrc[i] = ei[ebase + e] - gbase;                                   \
            edst[i] = ei[ETOT + ebase + e] - gbase;                            \
            eww[i]  = ew[ebase + e];                                           \
        }                                                                      \
    }                                                                          \
    ends[tid] = 0;                                                             \
    PRE                                                                        \
    __syncthreads();                                                           \
    _Pragma("unroll")                                                          \
    for (int i = 0; i < EPT; i++)                                              \
        if (i < ne) atomicAdd(&ends[edst[i]], 1);                              \
    __syncthreads();                                                           \
    int v = ends[tid];                                                         \
    int sc = v;                                                                \
    _Pragma("unroll")                                                          \
    for (int m = 1; m < 64; m <<= 1) {                                         \
        int t = __shfl_up(sc, m);                                              \
        if (lane >= m) sc += t;                                                \
    }                                                                          \
    if (lane == 63) wpart[wid] = sc;                                           \
    __syncthreads();                                                           \
    if (tid < 16) {                                                            \
        int s2 = wpart[tid];                                                   \
        _Pragma("unroll")                                                      \
        for (int m = 1; m < 16; m <<= 1) {                                     \
            int t = __shfl_up(s2, m);                                          \
            if (tid >= m) s2 += t;                                             \
        }                                                                      \
        wpart[tid] = s2;                                                       \
    }                                                                          \
    __syncthreads();                                                           \
    int incl = sc + (wid > 0 ? wpart[wid - 1] : 0);                            \
    ends[tid] = incl;                                                          \
    posc[tid] = incl - v;                                                      \
    __syncthreads();                                                           \
    _Pragma("unroll")                                                          \
    for (int i = 0; i < EPT; i++)                                              \
        if (i < ne) {                                                          \
            int p = atomicAdd(&posc[edst[i]], 1);                              \
            csr[p] = ((unsigned)f2bf(eww[i]) << 16) | (unsigned)esrc[i];       \
        }                                                                      \
    __syncthreads();                                                           \
} while (0)

// ---- wsum -> dl; y=dinv*x in place (full graph, bit-exact) ----
#define WSUM_BODY() do {                                                       \
    if (tid < N_PER) {                                                         \
        int s0i = tid ? ends[tid - 1] : 0;                                     \
        int e0i = ends[tid];                                                   \
        float s0 = 0.f, s1 = 0.f;                                              \
        int k = s0i;                                                           \
        for (; k + 2 <= e0i; k += 2) { s0 += upk(csr[k]); s1 += upk(csr[k + 1]); } \
        if (k < e0i) s0 += upk(csr[k]);                                        \
        float dmy = rsqrtf(s0 + s1 + 1.0f);                                    \
        dl[tid] = dmy;                                                         \
        xl[tid * 3 + 0] *= dmy;                                                \
        xl[tid * 3 + 1] *= dmy;                                                \
        xl[tid * 3 + 2] *= dmy;                                                \
    }                                                                          \
    __syncthreads();                                                           \
} while (0)

// conv1 gather for one node (bit-exact inner loop)
#define CONV1_NODE(NODE) do {                                                  \
    int node_ = (NODE);                                                        \
    int s0_ = node_ ? ends[node_ - 1] : 0;                                     \
    int e0_ = ends[node_];                                                     \
    float dm_ = dl[node_];                                                     \
    float a0 = xl[node_ * 3 + 0], a1 = xl[node_ * 3 + 1], a2 = xl[node_ * 3 + 2]; \
    for (int k = s0_; k < e0_; k++) {                                          \
        unsigned q = csr[k];                                                   \
        int i0 = (int)(q & 0xFFFFu) * 3;                                       \
        float wv = upk(q);                                                     \
        a0 += wv * xl[i0]; a1 += wv * xl[i0 + 1]; a2 += wv * xl[i0 + 2];       \
    }                                                                          \
    aggv[node_ * 3 + 0] = dm_ * a0;                                            \
    aggv[node_ * 3 + 1] = dm_ * a1;                                            \
    aggv[node_ * 3 + 2] = dm_ * a2;                                            \
} while (0)

// W1 for one ORIGINAL wave id OW (exact original node sequence OW, OW+16, ...)
#define W1_WAVE(OW, PXSTORE) do {                                              \
    int ow_ = (OW);                                                            \
    float w0 = w1[lane], w1v = w1[64 + lane], w2v = w1[128 + lane], bf = b1[lane]; \
    float px = 0.f;                                                            \
    int chunk = (lane & 31) >> 3;                                              \
    int word  = ((lane >= 32) ? 2 : 0) + ((lane & 7) >> 2);                    \
    for (int node = ow_; node < N_PER; node += 16) {                           \
        float a0 = aggv[node * 3], a1 = aggv[node * 3 + 1], a2 = aggv[node * 3 + 2]; \
        float hv = fmaxf(a0 * w0 + a1 * w1v + a2 * w2v + bf, 0.f);             \
        px += hv;                                                              \
        unsigned byte = enc_fp8(dl[node] * hv);                                \
        unsigned t1 = __shfl_xor(byte, 1);                                     \
        unsigned v16 = (lane & 1) ? (t1 | (byte << 8)) : (byte | (t1 << 8));   \
        unsigned t2 = __shfl_xor(v16, 2);                                      \
        unsigned v32 = (lane & 2) ? (t2 | (v16 << 16)) : (v16 | (t2 << 16));   \
        if ((lane & 3) == 0) {                                                 \
            int cs = chunk ^ ((node >> 1) & 3);                                \
            *(unsigned*)(zs + node * 64 + cs * 16 + word * 4) = v32;           \
        }                                                                      \
    }                                                                          \
    PXSTORE                                                                    \
} while (0)

// conv2 aggregation for one TI; results into named short8 AF0/AF1.
#define CONV2_TI(TI, AF0, AF1) do {                                            \
    const int t_ = wid + (TI) * 16;                                            \
    const int li_ = t_ * 16 + nloc;                                            \
    const bool valid_ = li_ < N_PER;                                           \
    float acc_[16];                                                            \
    int s_ = 0, cn_ = 0;                                                       \
    if (valid_) {                                                              \
        uint4 rv_ = *(const uint4*)(zs + li_ * 64 + ((kgrp ^ ((li_ >> 1) & 3)) << 4)); \
        _Pragma("unroll")                                                      \
        for (int j = 0; j < 4; j++) {                                          \
            acc_[j]      = dec_raw((rv_.x >> (8 * j)) & 0x7Fu);                \
            acc_[4 + j]  = dec_raw((rv_.y >> (8 * j)) & 0x7Fu);                \
            acc_[8 + j]  = dec_raw((rv_.z >> (8 * j)) & 0x7Fu);                \
            acc_[12 + j] = dec_raw((rv_.w >> (8 * j)) & 0x7Fu);                \
        }                                                                      \
        s_ = li_ ? ends[li_ - 1] : 0;                                          \
        cn_ = ends[li_] - s_;                                                  \
    } else {                                                                   \
        _Pragma("unroll")                                                      \
        for (int j = 0; j < 16; j++) acc_[j] = 0.f;                            \
    }                                                                          \
    int mx_ = cn_;                                                             \
    _Pragma("unroll")                                                          \
    for (int m = 1; m < 16; m <<= 1) mx_ = max(mx_, __shfl_xor(mx_, m));       \
    for (int k = 0; k < mx_; k++) {                                            \
        if (k < cn_) {                                                         \
            unsigned q_ = csr[s_ + k];                                         \
            int src_ = (int)(q_ & 0xFFFFu);                                    \
            float wv_ = upk(q_);                                               \
            uint4 rv_ = *(const uint4*)(zs + src_ * 64 + ((kgrp ^ ((src_ >> 1) & 3)) << 4)); \
            _Pragma("unroll")                                                  \
            for (int j = 0; j < 4; j++) {                                      \
                acc_[j]      += wv_ * dec_raw((rv_.x >> (8 * j)) & 0x7Fu);     \
                acc_[4 + j]  += wv_ * dec_raw((rv_.y >> (8 * j)) & 0x7Fu);     \
                acc_[8 + j]  += wv_ * dec_raw((rv_.z >> (8 * j)) & 0x7Fu);     \
                acc_[12 + j] += wv_ * dec_raw((rv_.w >> (8 * j)) & 0x7Fu);     \
            }                                                                  \
        }                                                                      \
    }                                                                          \
    float scale_ = (valid_ ? dl[li_] : 0.f) * 0x1p120f;                        \
    _Pragma("unroll")                                                          \
    for (int j = 0; j < 8; j++) {                                              \
        AF0[j] = (short)f2bf(scale_ * acc_[j]);                                \
        AF1[j] = (short)f2bf(scale_ * acc_[8 + j]);                            \
    }                                                                          \
} while (0)

// W2 MFMA + epilogue for one TI; KEYS may be LDS or global pointer.
#define W2_TI(TI, AF0, AF1, KEYS) do {                                         \
    const int t_ = wid + (TI) * 16;                                            \
    if (t_ < 63) {                                                             \
        float4_ accv_[4];                                                      \
        _Pragma("unroll")                                                      \
        for (int c = 0; c < 4; ++c) accv_[c] = (float4_){0.f, 0.f, 0.f, 0.f};  \
        _Pragma("unroll")                                                      \
        for (int c = 0; c < 4; ++c) {                                          \
            accv_[c] = __builtin_amdgcn_mfma_f32_16x16x32_bf16(AF0, Bf[0][c], accv_[c], 0, 0, 0); \
            accv_[c] = __builtin_amdgcn_mfma_f32_16x16x32_bf16(AF1, Bf[1][c], accv_[c], 0, 0, 0); \
        }                                                                      \
        _Pragma("unroll")                                                      \
        for (int r2 = 0; r2 < 4; ++r2) {                                       \
            int li2_ = t_ * 16 + kgrp * 4 + r2;                                \
            bool valid2_ = li2_ < N_PER;                                       \
            float sp_ = 0.f;                                                   \
            _Pragma("unroll")                                                  \
            for (int c = 0; c < 4; ++c) {                                      \
                float hv_ = fmaxf(accv_[c][r2] + b2c[c], 0.f);                 \
                sp_ += hv_ * pwc[c];                                           \
                if (valid2_) zs[li2_ * 64 + c * 16 + nloc] = (unsigned char)enc_fp8(hv_); \
            }                                                                  \
            _Pragma("unroll")                                                  \
            for (int m = 1; m < 16; m <<= 1) sp_ += __shfl_xor(sp_, m);        \
            if (valid2_ && nloc == 0) {                                        \
                float scv_ = tanhf(sp_ * invn);                                \
                unsigned bits_ = __float_as_uint(scv_);                        \
                unsigned u_ = (bits_ & 0x80000000u) ? ~bits_ : (bits_ | 0x80000000u); \
                (KEYS)[li2_] = ((unsigned long long)u_ << 32) | (unsigned)(1023 - li2_); \
            }                                                                  \
        }                                                                      \
    }                                                                          \
} while (0)

#define W2_SETUP() do {                                                        \
    _Pragma("unroll")                                                          \
    for (int kh = 0; kh < 2; ++kh)                                             \
        _Pragma("unroll")                                                      \
        for (int c = 0; c < 4; ++c) {                                          \
            short8 t;                                                          \
            _Pragma("unroll")                                                  \
            for (int j = 0; j < 8; ++j)                                        \
                t[j] = (short)f2bf(w2[(kh * 32 + kgrp * 8 + j) * 64 + c * 16 + nloc]); \
            Bf[kh][c] = t;                                                     \
        }                                                                      \
    _Pragma("unroll")                                                          \
    for (int c = 0; c < 4; ++c) {                                              \
        b2c[c] = b2[c * 16 + nloc];                                            \
        pwc[c] = pw[c * 16 + nloc];                                            \
    }                                                                          \
    {                                                                          \
        float p = pw[lane], pn = p * p;                                        \
        _Pragma("unroll")                                                      \
        for (int m = 32; m; m >>= 1) pn += __shfl_xor(pn, m);                  \
        invn = rsqrtf(pn);                                                     \
    }                                                                          \
} while (0)

// sort + topk-mean + MLP tail.
#define TAIL_BODY(OUTIDX) do {                                                 \
    {                                                                          \
        unsigned long long key = keys[tid];                                    \
        for (int k = 2; k <= 1024; k <<= 1) {                                  \
            for (int j = k >> 1; j > 0; j >>= 1) {                             \
                bool desc = (tid & k) == 0;                                    \
                unsigned long long p;                                          \
                if (j >= 64) {                                                 \
                    keys[tid] = key;                                           \
                    __syncthreads();                                           \
                    p = keys[tid ^ j];                                         \
                    __syncthreads();                                           \
                } else {                                                       \
                    p = __shfl_xor(key, j);                                    \
                }                                                              \
                bool low = (tid & j) == 0;                                     \
                bool sw = low ? (desc ? (key < p) : (key > p))                 \
                              : (desc ? (p < key) : (p > key));                \
                if (sw) key = p;                                               \
            }                                                                  \
        }                                                                      \
        keys[tid] = key;                                                       \
    }                                                                          \
    __syncthreads();                                                           \
    {                                                                          \
        int f = tid & 63, w16 = tid >> 6;                                      \
        float acc2 = 0.f;                                                      \
        for (int r = w16; r < KSEL; r += 16) {                                 \
            unsigned long long key = keys[r];                                  \
            int idx = 1023 - (int)(key & 0xFFFFFFFFu);                         \
            unsigned u = (unsigned)(key >> 32);                                \
            unsigned bits = (u & 0x80000000u) ? (u & 0x7FFFFFFFu) : ~u;        \
            float valS = __uint_as_float(bits) * 0x1p120f;                     \
            acc2 += valS * dec_raw((unsigned)zs[idx * 64 + f] & 0x7Fu);        \
        }                                                                      \
        red[tid] = acc2;                                                       \
    }                                                                          \
    __syncthreads();                                                           \
    if (tid < 64) {                                                            \
        float s2 = 0.f;                                                        \
        for (int ww = 0; ww < 16; ww++) s2 += red[ww * 64 + tid];              \
        zbuf[tid] = x1b[tid] + s2 * (1.0f / KSEL);                             \
    }                                                                          \
    __syncthreads();                                                           \
    if (tid < 64) {                                                            \
        float a = l1b[tid];                                                    \
        for (int k = 0; k < 64; k++) a += zbuf[k] * l1w[k * 64 + tid];         \
        a1buf[tid] = fmaxf(a, 0.f);                                            \
    }                                                                          \
    __syncthreads();                                                           \
    if (tid < 32) {                                                            \
        float a = l2b[tid];                                                    \
        for (int k = 0; k < 64; k++) a += a1buf[k] * l2w[k * 32 + tid];        \
        a2buf[tid] = fmaxf(a, 0.f);                                            \
    }                                                                          \
    __syncthreads();                                                           \
    if (tid == 0) {                                                            \
        float t = l3b[0];                                                      \
        for (int k = 0; k < 32; k++) t += a2buf[k] * l3w[k];                   \
        out[OUTIDX] = 1.0f / (1.0f + expf(-t));                                \
    }                                                                          \
} while (0)

#define SMEM_DECLS()                                                           \
    __shared__ __align__(16) unsigned char smem[136832];                       \
    unsigned char* zs = smem;                                                  \
    float* xl = (float*)smem;                                                  \
    unsigned* csr = (unsigned*)(smem + 64000);                                 \
    int*   ends = (int*)(smem + 112000);                                       \
    float* dl   = (float*)(smem + 116096);                                     \
    int*   posc = (int*)(smem + 116096);                                       \
    int*   wpart = (int*)(smem + 120192);                                      \
    float* x1b   = (float*)(smem + 120192);                                    \
    unsigned char* uA = smem + 120448;                                         \
    float* aggv = (float*)uA;                                                  \
    (void)posc; (void)wpart; (void)aggv; (void)x1b; (void)zs;

// ===== k_pair2: ONE dispatch, 2 blocks/graph, front AND conv2 split =====
// Both: build CSR (dup, free elapsed) + wsum (dup) + conv1/W1 own parity.
// Sync1 (ws, release/acquire, bounded spin; 200 blocks <= 256 CUs so pairs
// are co-resident — r7-proven): exchange z parity halves.
// conv2+W2 own contiguous half. Sync2: P1 ships h2-half+keys; P0 tail.
__global__ __launch_bounds__(1024)
__attribute__((amdgpu_waves_per_eu(4, 4))) void k_pair2(
    const int* __restrict__ ei, const float* __restrict__ ew,
    const float* __restrict__ x,
    const float* __restrict__ w1, const float* __restrict__ b1,
    const float* __restrict__ w2, const float* __restrict__ b2,
    const float* __restrict__ pw,
    const float* __restrict__ l1w, const float* __restrict__ l1b,
    const float* __restrict__ l2w, const float* __restrict__ l2b,
    const float* __restrict__ l3w, const float* __restrict__ l3b,
    float* __restrict__ out, unsigned char* __restrict__ ws) {
    SMEM_DECLS();
    int g = blockIdx.x >> 1, h = blockIdx.x & 1, tid = threadIdx.x;
    int wid = tid >> 6, lane = tid & 63;
    int gbase = g * N_PER, ebase = g * E_PER;
    unsigned* flag1 = (unsigned*)(ws + FLAG1B);
    unsigned* flag2 = (unsigned*)(ws + FLAG2B);
    unsigned char* zx = ws + ZXB + (size_t)g * 64000;
    float* sredx = (float*)(ws + SREDXB + (size_t)g * 4096);
    unsigned char* h2x = ws + H2XB + (size_t)g * 32768;
    unsigned long long* kx = (unsigned long long*)(ws + KEYXB + (size_t)g * 4096);

    BUILD_BODY(for (int i = tid; i < N_PER * 3; i += 1024) xl[i] = x[(size_t)gbase * 3 + i];);
    WSUM_BODY();
    if (tid < 500) CONV1_NODE(2 * tid + h);       // own parity nodes
    __syncthreads();
    if (wid < 8)
        W1_WAVE(2 * wid + h, { sredx[ow_ * 64 + lane] = px; });
    __syncthreads();
    // ---- publish own-parity z rows; sync1; import partner parity ----
    {
        uint4* zw = (uint4*)zx;
        const uint4* zv = (const uint4*)zs;
        for (int i = tid; i < 4000; i += 1024)
            if (((i >> 2) & 1) == h) zw[i] = zv[i];
    }
    __syncthreads();
    if (tid == 0)
        __hip_atomic_store(&flag1[g * 2 + h], 1u, __ATOMIC_RELEASE,
                           __HIP_MEMORY_SCOPE_AGENT);
    if (tid == 0) {
        for (int it = 0; it < SPINCAP; ++it) {    // ~40ms cap: no hang
            if (__hip_atomic_load(&flag1[g * 2 + (1 - h)], __ATOMIC_ACQUIRE,
                                  __HIP_MEMORY_SCOPE_AGENT) != 0u) break;
            __builtin_amdgcn_s_sleep(8);
        }
    }
    __syncthreads();
    {   // per-thread acquire (visibility insurance), then import
        unsigned f1 = __hip_atomic_load(&flag1[g * 2 + (1 - h)], __ATOMIC_ACQUIRE,
                                        __HIP_MEMORY_SCOPE_AGENT);
        asm volatile("" :: "s"(f1));
        const uint4* zr = (const uint4*)zx;
        uint4* zd = (uint4*)zs;
        for (int i = tid; i < 4000; i += 1024)
            if (((i >> 2) & 1) == (1 - h)) zd[i] = zr[i];
    }
    __syncthreads();
    // ---- conv2+W2 own contiguous half ----
    int kgrp = lane >> 4, nloc = lane & 15;
    const int tiA = h * 2, tiB = h * 2 + 1;
    short8 AfAa, AfAb, AfBa, AfBb;
    CONV2_TI(tiA, AfAa, AfAb);
    CONV2_TI(tiB, AfBa, AfBb);
    __syncthreads();   // all z reads done; zs half may become h2
    unsigned long long* keys = (unsigned long long*)uA;
    {
        short8 Bf[2][4]; float b2c[4], pwc[4], invn;
        W2_SETUP();
        if (tid >= N_PER) keys[tid] = 0ull;       // pads (in h1's range)
        W2_TI(tiA, AfAa, AfAb, keys);
        W2_TI(tiB, AfBa, AfBb, keys);
    }
    __syncthreads();
    // ---- sync2: P1 publishes h2-half + keys-half; P0 receives + tail ----
    if (h) {
        const uint4* srcv = (const uint4*)(zs + 32768);   // h2 rows 512..999
        uint4* dstv = (uint4*)h2x;
        for (int i = tid; i < 1952; i += 1024) dstv[i] = srcv[i];
        for (int i = tid; i < 512; i += 1024) kx[i] = keys[512 + i];
        __syncthreads();
        if (tid == 0)
            __hip_atomic_store(&flag2[g], 1u, __ATOMIC_RELEASE,
                               __HIP_MEMORY_SCOPE_AGENT);
        return;
    }
    if (tid == 0) {
        for (int it = 0; it < SPINCAP; ++it) {
            if (__hip_atomic_load(&flag2[g], __ATOMIC_ACQUIRE,
                                  __HIP_MEMORY_SCOPE_AGENT) != 0u) break;
            __builtin_amdgcn_s_sleep(8);
        }
    }
    __syncthreads();
    {
        unsigned f2 = __hip_atomic_load(&flag2[g], __ATOMIC_ACQUIRE,
                                        __HIP_MEMORY_SCOPE_AGENT);
        asm volatile("" :: "s"(f2));
        uint4* dstv = (uint4*)(zs + 32768);
        const uint4* srcv = (const uint4*)h2x;
        for (int i = tid; i < 1952; i += 1024) dstv[i] = srcv[i];
        for (int i = tid; i < 512; i += 1024) keys[512 + i] = kx[i];
        if (tid < 64) {   // x1b from wave partials, original order r=0..15
            float t = 0.f;
            for (int r = 0; r < 16; r++) t += sredx[r * 64 + tid];
            x1b[tid] = t * (1.0f / N_PER);
        }
    }
    __syncthreads();
    float* red   = (float*)(uA + 8192);
    float* a1buf = (float*)(uA + 12288);
    float* a2buf = (float*)(uA + 12544);
    float* zbuf  = (float*)(uA + 12672);
    TAIL_BODY(g);
}

// ===== fallback: r4-proven fused single kernel (ws too small) ====
__global__ __launch_bounds__(1024)
__attribute__((amdgpu_waves_per_eu(4, 4))) void k_all_single(
    const int* __restrict__ ei, const float* __restrict__ ew,
    const float* __restrict__ x,
    const float* __restrict__ w1, const float* __restrict__ b1,
    const float* __restrict__ w2, const float* __restrict__ b2,
    const float* __restrict__ pw,
    const float* __restrict__ l1w, const float* __restrict__ l1b,
    const float* __restrict__ l2w, const float* __restrict__ l2b,
    const float* __restrict__ l3w, const float* __restrict__ l3b,
    float* __restrict__ out) {
    SMEM_DECLS();
    int g = blockIdx.x, tid = threadIdx.x;
    int wid = tid >> 6, lane = tid & 63;
    int gbase = g * N_PER, ebase = g * E_PER;
    BUILD_BODY(for (int i = tid; i < N_PER * 3; i += 1024) xl[i] = x[(size_t)gbase * 3 + i];);
    WSUM_BODY();
    if (tid < N_PER) CONV1_NODE(tid);
    __syncthreads();
    {
        float* sred = (float*)(uA + 12288);
        if (wid < 16) W1_WAVE(wid, { sred[ow_ * 64 + lane] = px; });
        __syncthreads();
        if (tid < 64) {
            float t = 0.f;
            for (int r = 0; r < 16; r++) t += sred[r * 64 + tid];
            x1b[tid] = t * (1.0f / N_PER);
        }
    }
    int kgrp = lane >> 4, nloc = lane & 15;
    short8 Af0a, Af0b, Af1a, Af1b, Af2a, Af2b, Af3a, Af3b;
    CONV2_TI(0, Af0a, Af0b);
    CONV2_TI(1, Af1a, Af1b);
    CONV2_TI(2, Af2a, Af2b);
    CONV2_TI(3, Af3a, Af3b);
    __syncthreads();
    unsigned long long* keys = (unsigned long long*)uA;
    {
        short8 Bf[2][4]; float b2c[4], pwc[4], invn;
        W2_SETUP();
        if (tid >= N_PER) keys[tid] = 0ull;
        W2_TI(0, Af0a, Af0b, keys);
        W2_TI(1, Af1a, Af1b, keys);
        W2_TI(2, Af2a, Af2b, keys);
        W2_TI(3, Af3a, Af3b, keys);
    }
    __syncthreads();
    float* red   = (float*)(uA + 8192);
    float* a1buf = (float*)(uA + 12288);
    float* a2buf = (float*)(uA + 12544);
    float* zbuf  = (float*)(uA + 12672);
    TAIL_BODY(g);
}

extern "C" void kernel_launch(void* const* d_in, const int* in_sizes, int n_in,
                              void* d_out, int out_size, void* d_ws, size_t ws_size,
                              hipStream_t stream) {
    const float* x   = (const float*)d_in[0];
    const int*   ei  = (const int*)d_in[1];
    const float* ew  = (const float*)d_in[2];
    const float* c1w = (const float*)d_in[4];
    const float* c1b = (const float*)d_in[5];
    const float* c2w = (const float*)d_in[6];
    const float* c2b = (const float*)d_in[7];
    const float* pw  = (const float*)d_in[8];
    const float* l1w = (const float*)d_in[9];
    const float* l1b = (const float*)d_in[10];
    const float* l2w = (const float*)d_in[11];
    const float* l2b = (const float*)d_in[12];
    const float* l3w = (const float*)d_in[13];
    const float* l3b = (const float*)d_in[14];
    float* out = (float*)d_out;
    (void)in_sizes; (void)n_in; (void)out_size;

    if (d_ws != nullptr && ws_size >= (size_t)WSNEED) {
        // zero sync flags (graph-capture-safe async memset on stream)
        hipMemsetAsync(d_ws, 0, 4096, stream);
        k_pair2<<<2 * B_G, 1024, 0, stream>>>(
            ei, ew, x, c1w, c1b, c2w, c2b, pw,
            l1w, l1b, l2w, l2b, l3w, l3b, out, (unsigned char*)d_ws);
    } else {
        k_all_single<<<B_G, 1024, 0, stream>>>(
            ei, ew, x, c1w, c1b, c2w, c2b, pw,
            l1w, l1b, l2w, l2b, l3w, l3b, out);
    }
}

// Round 12
// 167.558 us; speedup vs baseline: 1.3271x; 1.3271x over previous
//
#include <hip/hip_runtime.h>

#define B_G   100
#define N_PER 1000
#define E_PER 12000
#define NTOT  (B_G * N_PER)
#define ETOT  (B_G * E_PER)
#define KSEL  800
#define EPT   12

// ---- workspace layout (bytes) ----
#define H2B    0u          // fp8 h2 [1000][64]/graph, stride 65536
#define KEYB   6553600u    // u64[1024]/graph, stride 8192
#define X1BB   7372800u    // f32[64]/graph, stride 256
#define WSNEED 7398400u

typedef __attribute__((ext_vector_type(8))) short short8;
typedef __attribute__((ext_vector_type(4))) float float4_;

__device__ __forceinline__ unsigned short f2bf(float f) {
    unsigned u = __float_as_uint(f);
    u += 0x7fffu + ((u >> 16) & 1u);          // RNE
    return (unsigned short)(u >> 16);
}
__device__ __forceinline__ float upk(unsigned q) {          // bf16 ew in hi16
    return __uint_as_float(q & 0xFFFF0000u);
}
// fp8 e4m3 (z>=0): raw decode = true_value * 2^-120 (exact, incl subnormals)
__device__ __forceinline__ float dec_raw(unsigned byte7f) { // pass (b&0x7f)
    return __uint_as_float(byte7f << 20);
}
__device__ __forceinline__ unsigned enc_fp8(float z) {      // z >= 0, z < 448
    unsigned u = __float_as_uint(z * 0x1p-120f);
    u += 0x7FFFFu + ((u >> 20) & 1u);                       // RNE at bit 20
    return u >> 20;
}

// ---- CSR build: edge load, count, scan, fill. Ends with a barrier. ----
#define BUILD_BODY(PRE) do {                                                   \
    int esrc[EPT], edst[EPT]; float eww[EPT];                                  \
    int ne = (tid < (E_PER - (EPT - 1) * 1024)) ? EPT : EPT - 1;               \
    _Pragma("unroll")                                                          \
    for (int i = 0; i < EPT; i++) {                                            \
        if (i < ne) {                                                          \
            int e = tid + i * 1024;                                            \
            esrc[i] = ei[ebase + e] - gbase;                                   \
            edst[i] = ei[ETOT + ebase + e] - gbase;                            \
            eww[i]  = ew[ebase + e];                                           \
        }                                                                      \
    }                                                                          \
    ends[tid] = 0;                                                             \
    PRE                                                                        \
    __syncthreads();                                                           \
    _Pragma("unroll")                                                          \
    for (int i = 0; i < EPT; i++)                                              \
        if (i < ne) atomicAdd(&ends[edst[i]], 1);                              \
    __syncthreads();                                                           \
    int v = ends[tid];                                                         \
    int sc = v;                                                                \
    _Pragma("unroll")                                                          \
    for (int m = 1; m < 64; m <<= 1) {                                         \
        int t = __shfl_up(sc, m);                                              \
        if (lane >= m) sc += t;                                                \
    }                                                                          \
    if (lane == 63) wpart[wid] = sc;                                           \
    __syncthreads();                                                           \
    if (tid < 16) {                                                            \
        int s2 = wpart[tid];                                                   \
        _Pragma("unroll")                                                      \
        for (int m = 1; m < 16; m <<= 1) {                                     \
            int t = __shfl_up(s2, m);                                          \
            if (tid >= m) s2 += t;                                             \
        }                                                                      \
        wpart[tid] = s2;                                                       \
    }                                                                          \
    __syncthreads();                                                           \
    int incl = sc + (wid > 0 ? wpart[wid - 1] : 0);                            \
    ends[tid] = incl;                                                          \
    posc[tid] = incl - v;                                                      \
    __syncthreads();                                                           \
    _Pragma("unroll")                                                          \
    for (int i = 0; i < EPT; i++)                                              \
        if (i < ne) {                                                          \
            int p = atomicAdd(&posc[edst[i]], 1);                              \
            csr[p] = ((unsigned)f2bf(eww[i]) << 16) | (unsigned)esrc[i];       \
        }                                                                      \
    __syncthreads();                                                           \
} while (0)

// ---- wsum -> dl; y=dinv*x in place (full graph, bit-exact) ----
#define WSUM_BODY() do {                                                       \
    if (tid < N_PER) {                                                         \
        int s0i = tid ? ends[tid - 1] : 0;                                     \
        int e0i = ends[tid];                                                   \
        float s0 = 0.f, s1 = 0.f;                                              \
        int k = s0i;                                                           \
        for (; k + 2 <= e0i; k += 2) { s0 += upk(csr[k]); s1 += upk(csr[k + 1]); } \
        if (k < e0i) s0 += upk(csr[k]);                                        \
        float dmy = rsqrtf(s0 + s1 + 1.0f);                                    \
        dl[tid] = dmy;                                                         \
        xl[tid * 3 + 0] *= dmy;                                                \
        xl[tid * 3 + 1] *= dmy;                                                \
        xl[tid * 3 + 2] *= dmy;                                                \
    }                                                                          \
    __syncthreads();                                                           \
} while (0)

// conv1 gather for one node (bit-exact inner loop)
#define CONV1_NODE(NODE) do {                                                  \
    int node_ = (NODE);                                                        \
    int s0_ = node_ ? ends[node_ - 1] : 0;                                     \
    int e0_ = ends[node_];                                                     \
    float dm_ = dl[node_];                                                     \
    float a0 = xl[node_ * 3 + 0], a1 = xl[node_ * 3 + 1], a2 = xl[node_ * 3 + 2]; \
    for (int k = s0_; k < e0_; k++) {                                          \
        unsigned q = csr[k];                                                   \
        int i0 = (int)(q & 0xFFFFu) * 3;                                       \
        float wv = upk(q);                                                     \
        a0 += wv * xl[i0]; a1 += wv * xl[i0 + 1]; a2 += wv * xl[i0 + 2];       \
    }                                                                          \
    aggv[node_ * 3 + 0] = dm_ * a0;                                            \
    aggv[node_ * 3 + 1] = dm_ * a1;                                            \
    aggv[node_ * 3 + 2] = dm_ * a2;                                            \
} while (0)

// W1 for one ORIGINAL wave id OW (exact original node sequence OW, OW+16, ...)
#define W1_WAVE(OW, PXSTORE) do {                                              \
    int ow_ = (OW);                                                            \
    float w0 = w1[lane], w1v = w1[64 + lane], w2v = w1[128 + lane], bf = b1[lane]; \
    float px = 0.f;                                                            \
    int chunk = (lane & 31) >> 3;                                              \
    int word  = ((lane >= 32) ? 2 : 0) + ((lane & 7) >> 2);                    \
    for (int node = ow_; node < N_PER; node += 16) {                           \
        float a0 = aggv[node * 3], a1 = aggv[node * 3 + 1], a2 = aggv[node * 3 + 2]; \
        float hv = fmaxf(a0 * w0 + a1 * w1v + a2 * w2v + bf, 0.f);             \
        px += hv;                                                              \
        unsigned byte = enc_fp8(dl[node] * hv);                                \
        unsigned t1 = __shfl_xor(byte, 1);                                     \
        unsigned v16 = (lane & 1) ? (t1 | (byte << 8)) : (byte | (t1 << 8));   \
        unsigned t2 = __shfl_xor(v16, 2);                                      \
        unsigned v32 = (lane & 2) ? (t2 | (v16 << 16)) : (v16 | (t2 << 16));   \
        if ((lane & 3) == 0) {                                                 \
            int cs = chunk ^ ((node >> 1) & 3);                                \
            *(unsigned*)(zs + node * 64 + cs * 16 + word * 4) = v32;           \
        }                                                                      \
    }                                                                          \
    PXSTORE                                                                    \
} while (0)

// conv2 aggregation for one TI; results into named short8 AF0/AF1.
#define CONV2_TI(TI, AF0, AF1) do {                                            \
    const int t_ = wid + (TI) * 16;                                            \
    const int li_ = t_ * 16 + nloc;                                            \
    const bool valid_ = li_ < N_PER;                                           \
    float acc_[16];                                                            \
    int s_ = 0, cn_ = 0;                                                       \
    if (valid_) {                                                              \
        uint4 rv_ = *(const uint4*)(zs + li_ * 64 + ((kgrp ^ ((li_ >> 1) & 3)) << 4)); \
        _Pragma("unroll")                                                      \
        for (int j = 0; j < 4; j++) {                                          \
            acc_[j]      = dec_raw((rv_.x >> (8 * j)) & 0x7Fu);                \
            acc_[4 + j]  = dec_raw((rv_.y >> (8 * j)) & 0x7Fu);                \
            acc_[8 + j]  = dec_raw((rv_.z >> (8 * j)) & 0x7Fu);                \
            acc_[12 + j] = dec_raw((rv_.w >> (8 * j)) & 0x7Fu);                \
        }                                                                      \
        s_ = li_ ? ends[li_ - 1] : 0;                                          \
        cn_ = ends[li_] - s_;                                                  \
    } else {                                                                   \
        _Pragma("unroll")                                                      \
        for (int j = 0; j < 16; j++) acc_[j] = 0.f;                            \
    }                                                                          \
    int mx_ = cn_;                                                             \
    _Pragma("unroll")                                                          \
    for (int m = 1; m < 16; m <<= 1) mx_ = max(mx_, __shfl_xor(mx_, m));       \
    for (int k = 0; k < mx_; k++) {                                            \
        if (k < cn_) {                                                         \
            unsigned q_ = csr[s_ + k];                                         \
            int src_ = (int)(q_ & 0xFFFFu);                                    \
            float wv_ = upk(q_);                                               \
            uint4 rv_ = *(const uint4*)(zs + src_ * 64 + ((kgrp ^ ((src_ >> 1) & 3)) << 4)); \
            _Pragma("unroll")                                                  \
            for (int j = 0; j < 4; j++) {                                      \
                acc_[j]      += wv_ * dec_raw((rv_.x >> (8 * j)) & 0x7Fu);     \
                acc_[4 + j]  += wv_ * dec_raw((rv_.y >> (8 * j)) & 0x7Fu);     \
                acc_[8 + j]  += wv_ * dec_raw((rv_.z >> (8 * j)) & 0x7Fu);     \
                acc_[12 + j] += wv_ * dec_raw((rv_.w >> (8 * j)) & 0x7Fu);     \
            }                                                                  \
        }                                                                      \
    }                                                                          \
    float scale_ = (valid_ ? dl[li_] : 0.f) * 0x1p120f;                        \
    _Pragma("unroll")                                                          \
    for (int j = 0; j < 8; j++) {                                              \
        AF0[j] = (short)f2bf(scale_ * acc_[j]);                                \
        AF1[j] = (short)f2bf(scale_ * acc_[8 + j]);                            \
    }                                                                          \
} while (0)

// W2 MFMA + epilogue for one TI; KEYS may be LDS or global pointer.
#define W2_TI(TI, AF0, AF1, KEYS) do {                                         \
    const int t_ = wid + (TI) * 16;                                            \
    if (t_ < 63) {                                                             \
        float4_ accv_[4];                                                      \
        _Pragma("unroll")                                                      \
        for (int c = 0; c < 4; ++c) accv_[c] = (float4_){0.f, 0.f, 0.f, 0.f};  \
        _Pragma("unroll")                                                      \
        for (int c = 0; c < 4; ++c) {                                          \
            accv_[c] = __builtin_amdgcn_mfma_f32_16x16x32_bf16(AF0, Bf[0][c], accv_[c], 0, 0, 0); \
            accv_[c] = __builtin_amdgcn_mfma_f32_16x16x32_bf16(AF1, Bf[1][c], accv_[c], 0, 0, 0); \
        }                                                                      \
        _Pragma("unroll")                                                      \
        for (int r2 = 0; r2 < 4; ++r2) {                                       \
            int li2_ = t_ * 16 + kgrp * 4 + r2;                                \
            bool valid2_ = li2_ < N_PER;                                       \
            float sp_ = 0.f;                                                   \
            _Pragma("unroll")                                                  \
            for (int c = 0; c < 4; ++c) {                                      \
                float hv_ = fmaxf(accv_[c][r2] + b2c[c], 0.f);                 \
                sp_ += hv_ * pwc[c];                                           \
                if (valid2_) zs[li2_ * 64 + c * 16 + nloc] = (unsigned char)enc_fp8(hv_); \
            }                                                                  \
            _Pragma("unroll")                                                  \
            for (int m = 1; m < 16; m <<= 1) sp_ += __shfl_xor(sp_, m);        \
            if (valid2_ && nloc == 0) {                                        \
                float scv_ = tanhf(sp_ * invn);                                \
                unsigned bits_ = __float_as_uint(scv_);                        \
                unsigned u_ = (bits_ & 0x80000000u) ? ~bits_ : (bits_ | 0x80000000u); \
                (KEYS)[li2_] = ((unsigned long long)u_ << 32) | (unsigned)(1023 - li2_); \
            }                                                                  \
        }                                                                      \
    }                                                                          \
} while (0)

#define W2_SETUP() do {                                                        \
    _Pragma("unroll")                                                          \
    for (int kh = 0; kh < 2; ++kh)                                             \
        _Pragma("unroll")                                                      \
        for (int c = 0; c < 4; ++c) {                                          \
            short8 t;                                                          \
            _Pragma("unroll")                                                  \
            for (int j = 0; j < 8; ++j)                                        \
                t[j] = (short)f2bf(w2[(kh * 32 + kgrp * 8 + j) * 64 + c * 16 + nloc]); \
            Bf[kh][c] = t;                                                     \
        }                                                                      \
    _Pragma("unroll")                                                          \
    for (int c = 0; c < 4; ++c) {                                              \
        b2c[c] = b2[c * 16 + nloc];                                            \
        pwc[c] = pw[c * 16 + nloc];                                            \
    }                                                                          \
    {                                                                          \
        float p = pw[lane], pn = p * p;                                        \
        _Pragma("unroll")                                                      \
        for (int m = 32; m; m >>= 1) pn += __shfl_xor(pn, m);                  \
        invn = rsqrtf(pn);                                                     \
    }                                                                          \
} while (0)

// sort + topk-mean + MLP tail.
#define TAIL_BODY(OUTIDX) do {                                                 \
    {                                                                          \
        unsigned long long key = keys[tid];                                    \
        for (int k = 2; k <= 1024; k <<= 1) {                                  \
            for (int j = k >> 1; j > 0; j >>= 1) {                             \
                bool desc = (tid & k) == 0;                                    \
                unsigned long long p;                                          \
                if (j >= 64) {                                                 \
                    keys[tid] = key;                                           \
                    __syncthreads();                                           \
                    p = keys[tid ^ j];                                         \
                    __syncthreads();                                           \
                } else {                                                       \
                    p = __shfl_xor(key, j);                                    \
                }                                                              \
                bool low = (tid & j) == 0;                                     \
                bool sw = low ? (desc ? (key < p) : (key > p))                 \
                              : (desc ? (p < key) : (p > key));                \
                if (sw) key = p;                                               \
            }                                                                  \
        }                                                                      \
        keys[tid] = key;                                                       \
    }                                                                          \
    __syncthreads();                                                           \
    {                                                                          \
        int f = tid & 63, w16 = tid >> 6;                                      \
        float acc2 = 0.f;                                                      \
        for (int r = w16; r < KSEL; r += 16) {                                 \
            unsigned long long key = keys[r];                                  \
            int idx = 1023 - (int)(key & 0xFFFFFFFFu);                         \
            unsigned u = (unsigned)(key >> 32);                                \
            unsigned bits = (u & 0x80000000u) ? (u & 0x7FFFFFFFu) : ~u;        \
            float valS = __uint_as_float(bits) * 0x1p120f;                     \
            acc2 += valS * dec_raw((unsigned)zs[idx * 64 + f] & 0x7Fu);        \
        }                                                                      \
        red[tid] = acc2;                                                       \
    }                                                                          \
    __syncthreads();                                                           \
    if (tid < 64) {                                                            \
        float s2 = 0.f;                                                        \
        for (int ww = 0; ww < 16; ww++) s2 += red[ww * 64 + tid];              \
        zbuf[tid] = x1b[tid] + s2 * (1.0f / KSEL);                             \
    }                                                                          \
    __syncthreads();                                                           \
    if (tid < 64) {                                                            \
        float a = l1b[tid];                                                    \
        for (int k = 0; k < 64; k++) a += zbuf[k] * l1w[k * 64 + tid];         \
        a1buf[tid] = fmaxf(a, 0.f);                                            \
    }                                                                          \
    __syncthreads();                                                           \
    if (tid < 32) {                                                            \
        float a = l2b[tid];                                                    \
        for (int k = 0; k < 64; k++) a += a1buf[k] * l2w[k * 32 + tid];        \
        a2buf[tid] = fmaxf(a, 0.f);                                            \
    }                                                                          \
    __syncthreads();                                                           \
    if (tid == 0) {                                                            \
        float t = l3b[0];                                                      \
        for (int k = 0; k < 32; k++) t += a2buf[k] * l3w[k];                   \
        out[OUTIDX] = 1.0f / (1.0f + expf(-t));                                \
    }                                                                          \
} while (0)

#define SMEM_DECLS()                                                           \
    __shared__ __align__(16) unsigned char smem[136832];                       \
    unsigned char* zs = smem;                                                  \
    float* xl = (float*)smem;                                                  \
    unsigned* csr = (unsigned*)(smem + 64000);                                 \
    int*   ends = (int*)(smem + 112000);                                       \
    float* dl   = (float*)(smem + 116096);                                     \
    int*   posc = (int*)(smem + 116096);                                       \
    int*   wpart = (int*)(smem + 120192);                                      \
    float* x1b   = (float*)(smem + 120192);                                    \
    unsigned char* uA = smem + 120448;                                         \
    float* aggv = (float*)uA;                                                  \
    (void)posc; (void)wpart; (void)aggv; (void)x1b; (void)zs;

// ===== k_mid2: r8's k_mid with the CSR build FUSED IN (r7-proven pattern).
// 2 blocks/graph; both build CSR + run full front (duplicated — pair blocks
// run concurrently so duplication costs no elapsed time, r11 lesson);
// conv2+W2 for own node half; h2-half + keys-half + x1b to ws. ====
__global__ __launch_bounds__(1024)
__attribute__((amdgpu_waves_per_eu(4, 4))) void k_mid2(
    const int* __restrict__ ei, const float* __restrict__ ew,
    const float* __restrict__ x,
    const float* __restrict__ w1, const float* __restrict__ b1,
    const float* __restrict__ w2, const float* __restrict__ b2,
    const float* __restrict__ pw, unsigned char* __restrict__ ws) {
    SMEM_DECLS();
    int g = blockIdx.x >> 1, half = blockIdx.x & 1, tid = threadIdx.x;
    int wid = tid >> 6, lane = tid & 63;
    int gbase = g * N_PER, ebase = g * E_PER;
    BUILD_BODY(for (int i = tid; i < N_PER * 3; i += 1024) xl[i] = x[(size_t)gbase * 3 + i];);
    WSUM_BODY();
    if (tid < N_PER) CONV1_NODE(tid);
    __syncthreads();
    {
        float* sred = (float*)(uA + 12288);
        if (wid < 16) W1_WAVE(wid, { sred[ow_ * 64 + lane] = px; });
        __syncthreads();
        if (tid < 64) {
            float t = 0.f;
            for (int r = 0; r < 16; r++) t += sred[r * 64 + tid];
            x1b[tid] = t * (1.0f / N_PER);
        }
    }
    int kgrp = lane >> 4, nloc = lane & 15;
    const int tiA = half * 2, tiB = half * 2 + 1;
    short8 AfAa, AfAb, AfBa, AfBb;
    CONV2_TI(tiA, AfAa, AfAb);
    CONV2_TI(tiB, AfBa, AfBb);
    __syncthreads();   // all z reads + sred reads done; uA may become keys
    unsigned long long* keys = (unsigned long long*)uA;
    {
        short8 Bf[2][4]; float b2c[4], pwc[4], invn;
        W2_SETUP();
        if (tid >= N_PER) keys[tid] = 0ull;
        W2_TI(tiA, AfAa, AfAb, keys);
        W2_TI(tiB, AfBa, AfBb, keys);
    }
    __syncthreads();
    {
        uint4* d = (uint4*)(ws + H2B + (size_t)g * 65536 + (size_t)half * 32768);
        const uint4* s = (const uint4*)(zs + half * 32768);
        int n = half ? 1952 : 2048;              // rows 512..999 vs 0..511
        for (int i = tid; i < n; i += 1024) d[i] = s[i];
        unsigned long long* kw =
            (unsigned long long*)(ws + KEYB + (size_t)g * 8192);
        for (int i = tid; i < 512; i += 1024)
            kw[half * 512 + i] = keys[half * 512 + i];
        if (!half && tid < 64)
            ((float*)(ws + X1BB + (size_t)g * 256))[tid] = x1b[tid];
    }
}

// ===== k_tail: 1 block/graph; sort + topk-mean + MLP (r8-proven) ====
__global__ __launch_bounds__(1024) void k_tail(
    const float* __restrict__ l1w, const float* __restrict__ l1b,
    const float* __restrict__ l2w, const float* __restrict__ l2b,
    const float* __restrict__ l3w, const float* __restrict__ l3b,
    float* __restrict__ out, const unsigned char* __restrict__ ws) {
    __shared__ __align__(16) unsigned char sm2[77184];
    unsigned char* zs = sm2;                                   // h2 [1000][64]
    unsigned long long* keys = (unsigned long long*)(sm2 + 64000);
    float* red   = (float*)(sm2 + 72192);
    float* x1b   = (float*)(sm2 + 76288);
    float* a1buf = (float*)(sm2 + 76544);
    float* a2buf = (float*)(sm2 + 76800);
    float* zbuf  = (float*)(sm2 + 76928);
    int g = blockIdx.x, tid = threadIdx.x;
    {
        uint4* hd = (uint4*)zs;
        const uint4* hs = (const uint4*)(ws + H2B + (size_t)g * 65536);
        for (int i = tid; i < 4000; i += 1024) hd[i] = hs[i];
        keys[tid] = ((const unsigned long long*)(ws + KEYB + (size_t)g * 8192))[tid];
        if (tid < 64) x1b[tid] = ((const float*)(ws + X1BB + (size_t)g * 256))[tid];
    }
    __syncthreads();
    TAIL_BODY(g);
}

// ===== fallback: r4-proven fused single kernel (ws too small) ====
__global__ __launch_bounds__(1024)
__attribute__((amdgpu_waves_per_eu(4, 4))) void k_all_single(
    const int* __restrict__ ei, const float* __restrict__ ew,
    const float* __restrict__ x,
    const float* __restrict__ w1, const float* __restrict__ b1,
    const float* __restrict__ w2, const float* __restrict__ b2,
    const float* __restrict__ pw,
    const float* __restrict__ l1w, const float* __restrict__ l1b,
    const float* __restrict__ l2w, const float* __restrict__ l2b,
    const float* __restrict__ l3w, const float* __restrict__ l3b,
    float* __restrict__ out) {
    SMEM_DECLS();
    int g = blockIdx.x, tid = threadIdx.x;
    int wid = tid >> 6, lane = tid & 63;
    int gbase = g * N_PER, ebase = g * E_PER;
    BUILD_BODY(for (int i = tid; i < N_PER * 3; i += 1024) xl[i] = x[(size_t)gbase * 3 + i];);
    WSUM_BODY();
    if (tid < N_PER) CONV1_NODE(tid);
    __syncthreads();
    {
        float* sred = (float*)(uA + 12288);
        if (wid < 16) W1_WAVE(wid, { sred[ow_ * 64 + lane] = px; });
        __syncthreads();
        if (tid < 64) {
            float t = 0.f;
            for (int r = 0; r < 16; r++) t += sred[r * 64 + tid];
            x1b[tid] = t * (1.0f / N_PER);
        }
    }
    int kgrp = lane >> 4, nloc = lane & 15;
    short8 Af0a, Af0b, Af1a, Af1b, Af2a, Af2b, Af3a, Af3b;
    CONV2_TI(0, Af0a, Af0b);
    CONV2_TI(1, Af1a, Af1b);
    CONV2_TI(2, Af2a, Af2b);
    CONV2_TI(3, Af3a, Af3b);
    __syncthreads();
    unsigned long long* keys = (unsigned long long*)uA;
    {
        short8 Bf[2][4]; float b2c[4], pwc[4], invn;
        W2_SETUP();
        if (tid >= N_PER) keys[tid] = 0ull;
        W2_TI(0, Af0a, Af0b, keys);
        W2_TI(1, Af1a, Af1b, keys);
        W2_TI(2, Af2a, Af2b, keys);
        W2_TI(3, Af3a, Af3b, keys);
    }
    __syncthreads();
    float* red   = (float*)(uA + 8192);
    float* a1buf = (float*)(uA + 12288);
    float* a2buf = (float*)(uA + 12544);
    float* zbuf  = (float*)(uA + 12672);
    TAIL_BODY(g);
}

extern "C" void kernel_launch(void* const* d_in, const int* in_sizes, int n_in,
                              void* d_out, int out_size, void* d_ws, size_t ws_size,
                              hipStream_t stream) {
    const float* x   = (const float*)d_in[0];
    const int*   ei  = (const int*)d_in[1];
    const float* ew  = (const float*)d_in[2];
    const float* c1w = (const float*)d_in[4];
    const float* c1b = (const float*)d_in[5];
    const float* c2w = (const float*)d_in[6];
    const float* c2b = (const float*)d_in[7];
    const float* pw  = (const float*)d_in[8];
    const float* l1w = (const float*)d_in[9];
    const float* l1b = (const float*)d_in[10];
    const float* l2w = (const float*)d_in[11];
    const float* l2b = (const float*)d_in[12];
    const float* l3w = (const float*)d_in[13];
    const float* l3b = (const float*)d_in[14];
    float* out = (float*)d_out;
    (void)in_sizes; (void)n_in; (void)out_size;

    if (d_ws != nullptr && ws_size >= (size_t)WSNEED) {
        unsigned char* ws = (unsigned char*)d_ws;
        k_mid2<<<2 * B_G, 1024, 0, stream>>>(ei, ew, x, c1w, c1b, c2w, c2b, pw, ws);
        k_tail<<<B_G, 1024, 0, stream>>>(l1w, l1b, l2w, l2b, l3w, l3b, out, ws);
    } else {
        k_all_single<<<B_G, 1024, 0, stream>>>(
            ei, ew, x, c1w, c1b, c2w, c2b, pw,
            l1w, l1b, l2w, l2b, l3w, l3b, out);
    }
}

// Round 13
// 166.261 us; speedup vs baseline: 1.3375x; 1.0078x over previous
//
#include <hip/hip_runtime.h>

#define B_G   100
#define N_PER 1000
#define E_PER 12000
#define NTOT  (B_G * N_PER)
#define ETOT  (B_G * E_PER)
#define KSEL  800
#define EPT   12

// ---- workspace layout (bytes) ----
#define H2B    0u          // fp8 h2 [1000][64]/graph, stride 65536
#define KEYB   6553600u    // u64[1024]/graph, stride 8192
#define X1BB   7372800u    // f32[64]/graph, stride 256
#define WSNEED 7398400u

typedef __attribute__((ext_vector_type(8))) short short8;
typedef __attribute__((ext_vector_type(4))) float float4_;

__device__ __forceinline__ unsigned short f2bf(float f) {
    unsigned u = __float_as_uint(f);
    u += 0x7fffu + ((u >> 16) & 1u);          // RNE
    return (unsigned short)(u >> 16);
}
__device__ __forceinline__ float upk(unsigned q) {          // bf16 ew in hi16
    return __uint_as_float(q & 0xFFFF0000u);
}
// fp8 e4m3 (z>=0): raw decode = true_value * 2^-120 (exact, incl subnormals)
__device__ __forceinline__ float dec_raw(unsigned byte7f) { // pass (b&0x7f)
    return __uint_as_float(byte7f << 20);
}
__device__ __forceinline__ unsigned enc_fp8(float z) {      // z >= 0, z < 448
    unsigned u = __float_as_uint(z * 0x1p-120f);
    u += 0x7FFFFu + ((u >> 20) & 1u);                       // RNE at bit 20
    return u >> 20;
}

// ---- CSR build: edge load, count, scan, fill. Ends with a barrier. ----
#define BUILD_BODY(PRE) do {                                                   \
    int esrc[EPT], edst[EPT]; float eww[EPT];                                  \
    int ne = (tid < (E_PER - (EPT - 1) * 1024)) ? EPT : EPT - 1;               \
    _Pragma("unroll")                                                          \
    for (int i = 0; i < EPT; i++) {                                            \
        if (i < ne) {                                                          \
            int e = tid + i * 1024;                                            \
            esrc[i] = ei[ebase + e] - gbase;                                   \
            edst[i] = ei[ETOT + ebase + e] - gbase;                            \
            eww[i]  = ew[ebase + e];                                           \
        }                                                                      \
    }                                                                          \
    ends[tid] = 0;                                                             \
    PRE                                                                        \
    __syncthreads();                                                           \
    _Pragma("unroll")                                                          \
    for (int i = 0; i < EPT; i++)                                              \
        if (i < ne) atomicAdd(&ends[edst[i]], 1);                              \
    __syncthreads();                                                           \
    int v = ends[tid];                                                         \
    int sc = v;                                                                \
    _Pragma("unroll")                                                          \
    for (int m = 1; m < 64; m <<= 1) {                                         \
        int t = __shfl_up(sc, m);                                              \
        if (lane >= m) sc += t;                                                \
    }                                                                          \
    if (lane == 63) wpart[wid] = sc;                                           \
    __syncthreads();                                                           \
    if (tid < 16) {                                                            \
        int s2 = wpart[tid];                                                   \
        _Pragma("unroll")                                                      \
        for (int m = 1; m < 16; m <<= 1) {                                     \
            int t = __shfl_up(s2, m);                                          \
            if (tid >= m) s2 += t;                                             \
        }                                                                      \
        wpart[tid] = s2;                                                       \
    }                                                                          \
    __syncthreads();                                                           \
    int incl = sc + (wid > 0 ? wpart[wid - 1] : 0);                            \
    ends[tid] = incl;                                                          \
    posc[tid] = incl - v;                                                      \
    __syncthreads();                                                           \
    _Pragma("unroll")                                                          \
    for (int i = 0; i < EPT; i++)                                              \
        if (i < ne) {                                                          \
            int p = atomicAdd(&posc[edst[i]], 1);                              \
            csr[p] = ((unsigned)f2bf(eww[i]) << 16) | (unsigned)esrc[i];       \
        }                                                                      \
    __syncthreads();                                                           \
} while (0)

// ---- wsum -> dl; y=dinv*x in place (full graph, bit-exact) ----
#define WSUM_BODY() do {                                                       \
    if (tid < N_PER) {                                                         \
        int s0i = tid ? ends[tid - 1] : 0;                                     \
        int e0i = ends[tid];                                                   \
        float s0 = 0.f, s1 = 0.f;                                              \
        int k = s0i;                                                           \
        for (; k + 2 <= e0i; k += 2) { s0 += upk(csr[k]); s1 += upk(csr[k + 1]); } \
        if (k < e0i) s0 += upk(csr[k]);                                        \
        float dmy = rsqrtf(s0 + s1 + 1.0f);                                    \
        dl[tid] = dmy;                                                         \
        xl[tid * 3 + 0] *= dmy;                                                \
        xl[tid * 3 + 1] *= dmy;                                                \
        xl[tid * 3 + 2] *= dmy;                                                \
    }                                                                          \
    __syncthreads();                                                           \
} while (0)

// conv1 gather for one node (bit-exact inner loop)
#define CONV1_NODE(NODE) do {                                                  \
    int node_ = (NODE);                                                        \
    int s0_ = node_ ? ends[node_ - 1] : 0;                                     \
    int e0_ = ends[node_];                                                     \
    float dm_ = dl[node_];                                                     \
    float a0 = xl[node_ * 3 + 0], a1 = xl[node_ * 3 + 1], a2 = xl[node_ * 3 + 2]; \
    for (int k = s0_; k < e0_; k++) {                                          \
        unsigned q = csr[k];                                                   \
        int i0 = (int)(q & 0xFFFFu) * 3;                                       \
        float wv = upk(q);                                                     \
        a0 += wv * xl[i0]; a1 += wv * xl[i0 + 1]; a2 += wv * xl[i0 + 2];       \
    }                                                                          \
    aggv[node_ * 3 + 0] = dm_ * a0;                                            \
    aggv[node_ * 3 + 1] = dm_ * a1;                                            \
    aggv[node_ * 3 + 2] = dm_ * a2;                                            \
} while (0)

// W1 for one ORIGINAL wave id OW (exact original node sequence OW, OW+16, ...)
#define W1_WAVE(OW, PXSTORE) do {                                              \
    int ow_ = (OW);                                                            \
    float w0 = w1[lane], w1v = w1[64 + lane], w2v = w1[128 + lane], bf = b1[lane]; \
    float px = 0.f;                                                            \
    int chunk = (lane & 31) >> 3;                                              \
    int word  = ((lane >= 32) ? 2 : 0) + ((lane & 7) >> 2);                    \
    for (int node = ow_; node < N_PER; node += 16) {                           \
        float a0 = aggv[node * 3], a1 = aggv[node * 3 + 1], a2 = aggv[node * 3 + 2]; \
        float hv = fmaxf(a0 * w0 + a1 * w1v + a2 * w2v + bf, 0.f);             \
        px += hv;                                                              \
        unsigned byte = enc_fp8(dl[node] * hv);                                \
        unsigned t1 = __shfl_xor(byte, 1);                                     \
        unsigned v16 = (lane & 1) ? (t1 | (byte << 8)) : (byte | (t1 << 8));   \
        unsigned t2 = __shfl_xor(v16, 2);                                      \
        unsigned v32 = (lane & 2) ? (t2 | (v16 << 16)) : (v16 | (t2 << 16));   \
        if ((lane & 3) == 0) {                                                 \
            int cs = chunk ^ ((node >> 1) & 3);                                \
            *(unsigned*)(zs + node * 64 + cs * 16 + word * 4) = v32;           \
        }                                                                      \
    }                                                                          \
    PXSTORE                                                                    \
} while (0)

// conv2 aggregation for one TI; results into named short8 AF0/AF1.
#define CONV2_TI(TI, AF0, AF1) do {                                            \
    const int t_ = wid + (TI) * 16;                                            \
    const int li_ = t_ * 16 + nloc;                                            \
    const bool valid_ = li_ < N_PER;                                           \
    float acc_[16];                                                            \
    int s_ = 0, cn_ = 0;                                                       \
    if (valid_) {                                                              \
        uint4 rv_ = *(const uint4*)(zs + li_ * 64 + ((kgrp ^ ((li_ >> 1) & 3)) << 4)); \
        _Pragma("unroll")                                                      \
        for (int j = 0; j < 4; j++) {                                          \
            acc_[j]      = dec_raw((rv_.x >> (8 * j)) & 0x7Fu);                \
            acc_[4 + j]  = dec_raw((rv_.y >> (8 * j)) & 0x7Fu);                \
            acc_[8 + j]  = dec_raw((rv_.z >> (8 * j)) & 0x7Fu);                \
            acc_[12 + j] = dec_raw((rv_.w >> (8 * j)) & 0x7Fu);                \
        }                                                                      \
        s_ = li_ ? ends[li_ - 1] : 0;                                          \
        cn_ = ends[li_] - s_;                                                  \
    } else {                                                                   \
        _Pragma("unroll")                                                      \
        for (int j = 0; j < 16; j++) acc_[j] = 0.f;                            \
    }                                                                          \
    int mx_ = cn_;                                                             \
    _Pragma("unroll")                                                          \
    for (int m = 1; m < 16; m <<= 1) mx_ = max(mx_, __shfl_xor(mx_, m));       \
    for (int k = 0; k < mx_; k++) {                                            \
        if (k < cn_) {                                                         \
            unsigned q_ = csr[s_ + k];                                         \
            int src_ = (int)(q_ & 0xFFFFu);                                    \
            float wv_ = upk(q_);                                               \
            uint4 rv_ = *(const uint4*)(zs + src_ * 64 + ((kgrp ^ ((src_ >> 1) & 3)) << 4)); \
            _Pragma("unroll")                                                  \
            for (int j = 0; j < 4; j++) {                                      \
                acc_[j]      += wv_ * dec_raw((rv_.x >> (8 * j)) & 0x7Fu);     \
                acc_[4 + j]  += wv_ * dec_raw((rv_.y >> (8 * j)) & 0x7Fu);     \
                acc_[8 + j]  += wv_ * dec_raw((rv_.z >> (8 * j)) & 0x7Fu);     \
                acc_[12 + j] += wv_ * dec_raw((rv_.w >> (8 * j)) & 0x7Fu);     \
            }                                                                  \
        }                                                                      \
    }                                                                          \
    float scale_ = (valid_ ? dl[li_] : 0.f) * 0x1p120f;                        \
    _Pragma("unroll")                                                          \
    for (int j = 0; j < 8; j++) {                                              \
        AF0[j] = (short)f2bf(scale_ * acc_[j]);                                \
        AF1[j] = (short)f2bf(scale_ * acc_[8 + j]);                            \
    }                                                                          \
} while (0)

// W2 MFMA + epilogue for one TI; KEYS may be LDS or global pointer.
#define W2_TI(TI, AF0, AF1, KEYS) do {                                         \
    const int t_ = wid + (TI) * 16;                                            \
    if (t_ < 63) {                                                             \
        float4_ accv_[4];                                                      \
        _Pragma("unroll")                                                      \
        for (int c = 0; c < 4; ++c) accv_[c] = (float4_){0.f, 0.f, 0.f, 0.f};  \
        _Pragma("unroll")                                                      \
        for (int c = 0; c < 4; ++c) {                                          \
            accv_[c] = __builtin_amdgcn_mfma_f32_16x16x32_bf16(AF0, Bf[0][c], accv_[c], 0, 0, 0); \
            accv_[c] = __builtin_amdgcn_mfma_f32_16x16x32_bf16(AF1, Bf[1][c], accv_[c], 0, 0, 0); \
        }                                                                      \
        _Pragma("unroll")                                                      \
        for (int r2 = 0; r2 < 4; ++r2) {                                       \
            int li2_ = t_ * 16 + kgrp * 4 + r2;                                \
            bool valid2_ = li2_ < N_PER;                                       \
            float sp_ = 0.f;                                                   \
            _Pragma("unroll")                                                  \
            for (int c = 0; c < 4; ++c) {                                      \
                float hv_ = fmaxf(accv_[c][r2] + b2c[c], 0.f);                 \
                sp_ += hv_ * pwc[c];                                           \
                if (valid2_) zs[li2_ * 64 + c * 16 + nloc] = (unsigned char)enc_fp8(hv_); \
            }                                                                  \
            _Pragma("unroll")                                                  \
            for (int m = 1; m < 16; m <<= 1) sp_ += __shfl_xor(sp_, m);        \
            if (valid2_ && nloc == 0) {                                        \
                float scv_ = tanhf(sp_ * invn);                                \
                unsigned bits_ = __float_as_uint(scv_);                        \
                unsigned u_ = (bits_ & 0x80000000u) ? ~bits_ : (bits_ | 0x80000000u); \
                (KEYS)[li2_] = ((unsigned long long)u_ << 32) | (unsigned)(1023 - li2_); \
            }                                                                  \
        }                                                                      \
    }                                                                          \
} while (0)

// per-wave early publish: this wave's 16-row h2 slab (it alone wrote those
// rows in W2_TI) straight to ws, overlapping other waves' compute. r13.
#define PUBLISH_WAVE(TI) do {                                                  \
    int R0_ = (wid + (TI) * 16) * 16;                                          \
    int boff_ = R0_ * 64 + lane * 16;                                          \
    if (boff_ < 64000)                                                         \
        *(uint4*)(h2g + boff_) = *(const uint4*)(zs + boff_);                  \
} while (0)

#define W2_SETUP() do {                                                        \
    _Pragma("unroll")                                                          \
    for (int kh = 0; kh < 2; ++kh)                                             \
        _Pragma("unroll")                                                      \
        for (int c = 0; c < 4; ++c) {                                          \
            short8 t;                                                          \
            _Pragma("unroll")                                                  \
            for (int j = 0; j < 8; ++j)                                        \
                t[j] = (short)f2bf(w2[(kh * 32 + kgrp * 8 + j) * 64 + c * 16 + nloc]); \
            Bf[kh][c] = t;                                                     \
        }                                                                      \
    _Pragma("unroll")                                                          \
    for (int c = 0; c < 4; ++c) {                                              \
        b2c[c] = b2[c * 16 + nloc];                                            \
        pwc[c] = pw[c * 16 + nloc];                                            \
    }                                                                          \
    {                                                                          \
        float p = pw[lane], pn = p * p;                                        \
        _Pragma("unroll")                                                      \
        for (int m = 32; m; m >>= 1) pn += __shfl_xor(pn, m);                  \
        invn = rsqrtf(pn);                                                     \
    }                                                                          \
} while (0)

// sort + topk-mean + MLP tail. topk reads h2 via shared-word broadcast (r13).
#define TAIL_BODY(OUTIDX) do {                                                 \
    {                                                                          \
        unsigned long long key = keys[tid];                                    \
        for (int k = 2; k <= 1024; k <<= 1) {                                  \
            for (int j = k >> 1; j > 0; j >>= 1) {                             \
                bool desc = (tid & k) == 0;                                    \
                unsigned long long p;                                          \
                if (j >= 64) {                                                 \
                    keys[tid] = key;                                           \
                    __syncthreads();                                           \
                    p = keys[tid ^ j];                                         \
                    __syncthreads();                                           \
                } else {                                                       \
                    p = __shfl_xor(key, j);                                    \
                }                                                              \
                bool low = (tid & j) == 0;                                     \
                bool sw = low ? (desc ? (key < p) : (key > p))                 \
                              : (desc ? (p < key) : (p > key));                \
                if (sw) key = p;                                               \
            }                                                                  \
        }                                                                      \
        keys[tid] = key;                                                       \
    }                                                                          \
    __syncthreads();                                                           \
    {                                                                          \
        int f = tid & 63, w16 = tid >> 6;                                      \
        float acc2 = 0.f;                                                      \
        for (int r = w16; r < KSEL; r += 16) {                                 \
            unsigned long long key = keys[r];                                  \
            int idx = 1023 - (int)(key & 0xFFFFFFFFu);                         \
            unsigned u = (unsigned)(key >> 32);                                \
            unsigned bits = (u & 0x80000000u) ? (u & 0x7FFFFFFFu) : ~u;        \
            float valS = __uint_as_float(bits) * 0x1p120f;                     \
            unsigned wv = *(const unsigned*)(zs + idx * 64 + (f & 60));        \
            acc2 += valS * dec_raw((wv >> ((f & 3) * 8)) & 0x7Fu);             \
        }                                                                      \
        red[tid] = acc2;                                                       \
    }                                                                          \
    __syncthreads();                                                           \
    if (tid < 64) {                                                            \
        float s2 = 0.f;                                                        \
        for (int ww = 0; ww < 16; ww++) s2 += red[ww * 64 + tid];              \
        zbuf[tid] = x1b[tid] + s2 * (1.0f / KSEL);                             \
    }                                                                          \
    __syncthreads();                                                           \
    if (tid < 64) {                                                            \
        float a = l1b[tid];                                                    \
        for (int k = 0; k < 64; k++) a += zbuf[k] * l1w[k * 64 + tid];         \
        a1buf[tid] = fmaxf(a, 0.f);                                            \
    }                                                                          \
    __syncthreads();                                                           \
    if (tid < 32) {                                                            \
        float a = l2b[tid];                                                    \
        for (int k = 0; k < 64; k++) a += a1buf[k] * l2w[k * 32 + tid];        \
        a2buf[tid] = fmaxf(a, 0.f);                                            \
    }                                                                          \
    __syncthreads();                                                           \
    if (tid == 0) {                                                            \
        float t = l3b[0];                                                      \
        for (int k = 0; k < 32; k++) t += a2buf[k] * l3w[k];                   \
        out[OUTIDX] = 1.0f / (1.0f + expf(-t));                                \
    }                                                                          \
} while (0)

#define SMEM_DECLS()                                                           \
    __shared__ __align__(16) unsigned char smem[136832];                       \
    unsigned char* zs = smem;                                                  \
    float* xl = (float*)smem;                                                  \
    unsigned* csr = (unsigned*)(smem + 64000);                                 \
    int*   ends = (int*)(smem + 112000);                                       \
    float* dl   = (float*)(smem + 116096);                                     \
    int*   posc = (int*)(smem + 116096);                                       \
    int*   wpart = (int*)(smem + 120192);                                      \
    float* x1b   = (float*)(smem + 120192);                                    \
    unsigned char* uA = smem + 120448;                                         \
    float* aggv = (float*)uA;                                                  \
    (void)posc; (void)wpart; (void)aggv; (void)x1b; (void)zs;

// ===== k_mid2: build + front (dup per pair) + conv2/W2 own half.
// r13: keys direct to ws (r9-proven); per-wave early h2 publish; x1b write
// overlapped with conv2; trailing barrier+publish block deleted. ====
__global__ __launch_bounds__(1024)
__attribute__((amdgpu_waves_per_eu(4, 4))) void k_mid2(
    const int* __restrict__ ei, const float* __restrict__ ew,
    const float* __restrict__ x,
    const float* __restrict__ w1, const float* __restrict__ b1,
    const float* __restrict__ w2, const float* __restrict__ b2,
    const float* __restrict__ pw, unsigned char* __restrict__ ws) {
    SMEM_DECLS();
    int g = blockIdx.x >> 1, half = blockIdx.x & 1, tid = threadIdx.x;
    int wid = tid >> 6, lane = tid & 63;
    int gbase = g * N_PER, ebase = g * E_PER;
    unsigned long long* kw = (unsigned long long*)(ws + KEYB + (size_t)g * 8192);
    unsigned char* h2g = ws + H2B + (size_t)g * 65536;
    BUILD_BODY(for (int i = tid; i < N_PER * 3; i += 1024) xl[i] = x[(size_t)gbase * 3 + i];);
    WSUM_BODY();
    if (tid < N_PER) CONV1_NODE(tid);
    __syncthreads();
    {
        float* sred = (float*)(uA + 12288);
        if (wid < 16) W1_WAVE(wid, { sred[ow_ * 64 + lane] = px; });
        __syncthreads();
        if (!half && tid < 64) {      // x1b straight to ws; overlaps conv2
            float t = 0.f;
            for (int r = 0; r < 16; r++) t += sred[r * 64 + tid];
            ((float*)(ws + X1BB + (size_t)g * 256))[tid] = t * (1.0f / N_PER);
        }
    }
    int kgrp = lane >> 4, nloc = lane & 15;
    const int tiA = half * 2, tiB = half * 2 + 1;
    short8 AfAa, AfAb, AfBa, AfBb;
    CONV2_TI(tiA, AfAa, AfAb);
    CONV2_TI(tiB, AfBa, AfBb);
    __syncthreads();   // all z reads done; zs rows may become h2
    {
        short8 Bf[2][4]; float b2c[4], pwc[4], invn;
        W2_SETUP();
        if (tid >= N_PER) kw[tid] = 0ull;        // pad keys (both halves: same value)
        W2_TI(tiA, AfAa, AfAb, kw);
        PUBLISH_WAVE(tiA);
        W2_TI(tiB, AfBa, AfBb, kw);
        PUBLISH_WAVE(tiB);
    }
    // kernel ends; stream order makes ws visible to k_tail
}

// ===== k_tail: 1 block/graph; sort + topk-mean + MLP ====
__global__ __launch_bounds__(1024) void k_tail(
    const float* __restrict__ l1w, const float* __restrict__ l1b,
    const float* __restrict__ l2w, const float* __restrict__ l2b,
    const float* __restrict__ l3w, const float* __restrict__ l3b,
    float* __restrict__ out, const unsigned char* __restrict__ ws) {
    __shared__ __align__(16) unsigned char sm2[77184];
    unsigned char* zs = sm2;                                   // h2 [1000][64]
    unsigned long long* keys = (unsigned long long*)(sm2 + 64000);
    float* red   = (float*)(sm2 + 72192);
    float* x1b   = (float*)(sm2 + 76288);
    float* a1buf = (float*)(sm2 + 76544);
    float* a2buf = (float*)(sm2 + 76800);
    float* zbuf  = (float*)(sm2 + 76928);
    int g = blockIdx.x, tid = threadIdx.x;
    {
        uint4* hd = (uint4*)zs;
        const uint4* hs = (const uint4*)(ws + H2B + (size_t)g * 65536);
        for (int i = tid; i < 4000; i += 1024) hd[i] = hs[i];
        keys[tid] = ((const unsigned long long*)(ws + KEYB + (size_t)g * 8192))[tid];
        if (tid < 64) x1b[tid] = ((const float*)(ws + X1BB + (size_t)g * 256))[tid];
    }
    __syncthreads();
    TAIL_BODY(g);
}

// ===== fallback: r4-proven fused single kernel (ws too small) ====
__global__ __launch_bounds__(1024)
__attribute__((amdgpu_waves_per_eu(4, 4))) void k_all_single(
    const int* __restrict__ ei, const float* __restrict__ ew,
    const float* __restrict__ x,
    const float* __restrict__ w1, const float* __restrict__ b1,
    const float* __restrict__ w2, const float* __restrict__ b2,
    const float* __restrict__ pw,
    const float* __restrict__ l1w, const float* __restrict__ l1b,
    const float* __restrict__ l2w, const float* __restrict__ l2b,
    const float* __restrict__ l3w, const float* __restrict__ l3b,
    float* __restrict__ out) {
    SMEM_DECLS();
    int g = blockIdx.x, tid = threadIdx.x;
    int wid = tid >> 6, lane = tid & 63;
    int gbase = g * N_PER, ebase = g * E_PER;
    BUILD_BODY(for (int i = tid; i < N_PER * 3; i += 1024) xl[i] = x[(size_t)gbase * 3 + i];);
    WSUM_BODY();
    if (tid < N_PER) CONV1_NODE(tid);
    __syncthreads();
    {
        float* sred = (float*)(uA + 12288);
        if (wid < 16) W1_WAVE(wid, { sred[ow_ * 64 + lane] = px; });
        __syncthreads();
        if (tid < 64) {
            float t = 0.f;
            for (int r = 0; r < 16; r++) t += sred[r * 64 + tid];
            x1b[tid] = t * (1.0f / N_PER);
        }
    }
    int kgrp = lane >> 4, nloc = lane & 15;
    short8 Af0a, Af0b, Af1a, Af1b, Af2a, Af2b, Af3a, Af3b;
    CONV2_TI(0, Af0a, Af0b);
    CONV2_TI(1, Af1a, Af1b);
    CONV2_TI(2, Af2a, Af2b);
    CONV2_TI(3, Af3a, Af3b);
    __syncthreads();
    unsigned long long* keys = (unsigned long long*)uA;
    {
        short8 Bf[2][4]; float b2c[4], pwc[4], invn;
        W2_SETUP();
        if (tid >= N_PER) keys[tid] = 0ull;
        W2_TI(0, Af0a, Af0b, keys);
        W2_TI(1, Af1a, Af1b, keys);
        W2_TI(2, Af2a, Af2b, keys);
        W2_TI(3, Af3a, Af3b, keys);
    }
    __syncthreads();
    float* red   = (float*)(uA + 8192);
    float* a1buf = (float*)(uA + 12288);
    float* a2buf = (float*)(uA + 12544);
    float* zbuf  = (float*)(uA + 12672);
    TAIL_BODY(g);
}

extern "C" void kernel_launch(void* const* d_in, const int* in_sizes, int n_in,
                              void* d_out, int out_size, void* d_ws, size_t ws_size,
                              hipStream_t stream) {
    const float* x   = (const float*)d_in[0];
    const int*   ei  = (const int*)d_in[1];
    const float* ew  = (const float*)d_in[2];
    const float* c1w = (const float*)d_in[4];
    const float* c1b = (const float*)d_in[5];
    const float* c2w = (const float*)d_in[6];
    const float* c2b = (const float*)d_in[7];
    const float* pw  = (const float*)d_in[8];
    const float* l1w = (const float*)d_in[9];
    const float* l1b = (const float*)d_in[10];
    const float* l2w = (const float*)d_in[11];
    const float* l2b = (const float*)d_in[12];
    const float* l3w = (const float*)d_in[13];
    const float* l3b = (const float*)d_in[14];
    float* out = (float*)d_out;
    (void)in_sizes; (void)n_in; (void)out_size;

    if (d_ws != nullptr && ws_size >= (size_t)WSNEED) {
        unsigned char* ws = (unsigned char*)d_ws;
        k_mid2<<<2 * B_G, 1024, 0, stream>>>(ei, ew, x, c1w, c1b, c2w, c2b, pw, ws);
        k_tail<<<B_G, 1024, 0, stream>>>(l1w, l1b, l2w, l2b, l3w, l3b, out, ws);
    } else {
        k_all_single<<<B_G, 1024, 0, stream>>>(
            ei, ew, x, c1w, c1b, c2w, c2b, pw,
            l1w, l1b, l2w, l2b, l3w, l3b, out);
    }
}